// Round 10
// baseline (151.221 us; speedup 1.0000x reference)
//
#include <hip/hip_runtime.h>

#define NN   2048
#define FF   512
#define CC   128
#define WROW 2560            // FF + NN
#define INFV 1.0e9f
#define NB   128             // blocks (1/CU used), all trivially co-resident
#define NT   1024
#define BN   16              // v-columns per block
#define HCAP 96              // dist-history capacity (kconv ~21 expected)

#define AL64(p)   __hip_atomic_load((p),  __ATOMIC_RELAXED, __HIP_MEMORY_SCOPE_AGENT)
#define AS64(p,v) __hip_atomic_store((p), (v), __ATOMIC_RELAXED, __HIP_MEMORY_SCOPE_AGENT)

// Exchange protocol: ONE self-describing 8B word per node per parity,
// (tag<<32)|float_bits, written by a single AS64 (atomic at the coherent
// point) by the owning wave right after its reduce. Data and signal travel
// together: no ack, no separate tag store, no vmcnt discipline in the loop.
// Consumers spin on exactly the two words they need, then the value is
// already in hand. Convergence is a block-local bitwise test with a
// grid-identical outcome (every block gathers the identical vector).
// Slot ping-pong is race-free by induction (publish s requires having seen
// all tags s-1). Replay safety: first call sees 0xAA.. poison tags (match
// nothing); later stale words carry values this deterministic computation
// would rewrite bitwise-identically, so even racy stale reads are correct.
struct WS {
    unsigned long long D[2][NN];     // tagged dists, parity ping-pong
    unsigned long long Suf[CC][8];   // tagged suffix sums (tag 0x40000000+kconv)
};

__device__ __forceinline__ unsigned long long pk(unsigned tag, float v) {
    return ((unsigned long long)tag << 32) | (unsigned long long)__float_as_uint(v);
}
__device__ __forceinline__ unsigned tg(unsigned long long e) { return (unsigned)(e >> 32); }
__device__ __forceinline__ float    vl(unsigned long long e) { return __uint_as_float((unsigned)e); }

__global__ __launch_bounds__(NT, 1)
void bf_lean(const float* __restrict__ adj,
             const float* __restrict__ emb,
             const float* __restrict__ W,
             const float* __restrict__ bias,
             const int*   __restrict__ srcp,
             float*       __restrict__ out,
             WS* ws, int out_size)
{
    __shared__ __align__(16) float adjT[BN * NN];   // 128 KB: adjT[vs][u]
    __shared__ __align__(16) float dist[NN];        // 8 KB
    __shared__ float hist[HCAP][BN];                // 6 KB own-dist history
    __shared__ float red16[BN];

    const int tid = threadIdx.x;
    const int b   = blockIdx.x;
    const int src = *srcp;
    const int q   = (b & 7) * 16 + (b >> 3);        // XCD-contiguous bands
    const int vb  = q * BN;

    // ---- publish own init words (consumers spin until visible) ----
    if (tid < BN)
        AS64(&ws->D[0][vb + tid], pk(0u, ((vb + tid) == src) ? 0.0f : INFV));

    // ---- stage adjacency slice: adjT[vs][u] = adj[u][vb+vs] (64B/row) ----
    #pragma unroll
    for (int it = 0; it < 8; ++it) {
        int r = tid + NT * it;
        int u = r >> 2, qc = (r & 3) * 4;
        float4 a = *(const float4*)(adj + (size_t)u * NN + vb + qc);
        adjT[(qc + 0) * NN + u] = a.x;
        adjT[(qc + 1) * NN + u] = a.y;
        adjT[(qc + 2) * NN + u] = a.z;
        adjT[(qc + 3) * NN + u] = a.w;
    }
    __syncthreads();

    const int vown = tid >> 6;            // wave w owns column vb+w
    const int lane = tid & 63;
    const int c0 = 2 * lane, c1 = c0 + 1; // output class pair
    float p0 = (tid == src) ? 0.0f : INFV;          // prev values (dist_{s-2})
    float p1 = ((tid + NT) == src) ? 0.0f : INFV;

    float acc0, acc1;
    { float d0 = ((vb + vown) == src) ? 0.0f : INFV;   // distances column 0
      acc0 = d0 * W[(size_t)c0 * WROW + FF];
      acc1 = d0 * W[(size_t)c1 * WROW + FF]; }

    int kconv = -1, hneg = 0;

    // ================= lean sweep loop: exchange + relax ONLY ================
    for (int s = 1; s <= NN; ++s) {
        const int pp = (s - 1) & 1;
        const unsigned want = (unsigned)(s - 1);
        unsigned long long e0 = AL64(&ws->D[pp][tid]);
        while (tg(e0) != want) { __builtin_amdgcn_s_sleep(1); e0 = AL64(&ws->D[pp][tid]); }
        unsigned long long e1 = AL64(&ws->D[pp][tid + NT]);
        while (tg(e1) != want) { __builtin_amdgcn_s_sleep(1); e1 = AL64(&ws->D[pp][tid + NT]); }
        float n0 = vl(e0), n1 = vl(e1);
        int ch = (n0 != p0) | (n1 != p1);             // bitwise, vs dist_{s-2}
        p0 = n0; p1 = n1;
        dist[tid] = n0; dist[tid + NT] = n1;
        int any = __syncthreads_or(ch);               // barrier + OR, fused
        if (s >= 2 && !any) { kconv = s - 1; break; } // grid-identical decision

        // relax own column over full LDS dist (conflict-free b128)
        float m = 4.0e9f;
        const float* ar = adjT + vown * NN;
        #pragma unroll
        for (int k = 0; k < 8; ++k) {
            int u = 4 * lane + 256 * k;
            float4 dd = *(const float4*)(dist + u);
            float4 aa = *(const float4*)(ar + u);
            m = fminf(m, fminf(fminf(dd.x + aa.x, dd.y + aa.y),
                               fminf(dd.z + aa.z, dd.w + aa.w)));
        }
        #pragma unroll
        for (int st = 1; st < 64; st <<= 1) m = fminf(m, __shfl_xor(m, st, 64));
        float nv = fminf(dist[vb + vown], m);

        if (lane == 0) {
            AS64(&ws->D[s & 1][vb + vown], pk((unsigned)s, nv));  // data+signal
            if (s <= HCAP) hist[s - 1][vown] = nv;                // defer fold
        }
        if (s > HCAP && s < NN) {                     // unreachable overflow path
            acc0 = fmaf(nv, W[(size_t)c0 * WROW + FF + s], acc0);
            acc1 = fmaf(nv, W[(size_t)c1 * WROW + FF + s], acc1);
        }
        __syncthreads();                              // dist[] safe to overwrite
    }

    // ================= post-loop (no sync coupling) ==========================
    if (kconv < 0) {
        // never converged: sweep NN was the probe; gather dist_NN, compare
        unsigned long long e0 = AL64(&ws->D[0][tid]);
        while (tg(e0) != (unsigned)NN) { __builtin_amdgcn_s_sleep(1); e0 = AL64(&ws->D[0][tid]); }
        unsigned long long e1 = AL64(&ws->D[0][tid + NT]);
        while (tg(e1) != (unsigned)NN) { __builtin_amdgcn_s_sleep(1); e1 = AL64(&ws->D[0][tid + NT]); }
        int ch = (vl(e0) != p0) | (vl(e1) != p1);
        hneg = __syncthreads_or(ch) ? 1 : 0;
    } else if (kconv >= 1 && kconv <= NN - 2) {
        // tail: columns kconv+1 .. NN-1 all equal final dist (in LDS)
        float ssum = 0.0f;                       // block b computes Suf[c = b]
        for (int i = kconv + 1 + tid; i <= NN - 1; i += NT)
            ssum += W[(size_t)b * WROW + FF + i];
        #pragma unroll
        for (int st = 1; st < 64; st <<= 1) ssum += __shfl_xor(ssum, st, 64);
        if (lane == 0) red16[vown] = ssum;
        __syncthreads();
        if (tid == 0) {
            float x = 0.0f;
            #pragma unroll
            for (int w = 0; w < BN; ++w) x += red16[w];
            AS64(&ws->Suf[b][0], pk(0x40000000u + (unsigned)kconv, x));
        }
        const unsigned wantS = 0x40000000u + (unsigned)kconv;   // grid-identical
        unsigned long long s0 = AL64(&ws->Suf[c0][0]);
        while (tg(s0) != wantS) { __builtin_amdgcn_s_sleep(1); s0 = AL64(&ws->Suf[c0][0]); }
        unsigned long long s1 = AL64(&ws->Suf[c1][0]);
        while (tg(s1) != wantS) { __builtin_amdgcn_s_sleep(1); s1 = AL64(&ws->Suf[c1][0]); }
        float dv = dist[vb + vown];              // final dist
        acc0 = fmaf(dv, vl(s0), acc0);
        acc1 = fmaf(dv, vl(s1), acc1);
    }

    // deferred dist-fold: columns 1 .. min(kconv, HCAP) from LDS history
    {
        int fmax = (kconv < 0) ? (NN - 1) : kconv;
        if (fmax > HCAP) fmax = HCAP;
        for (int s2 = 1; s2 <= fmax; ++s2) {
            float dv = hist[s2 - 1][vown];       // same-wave LDS broadcast
            acc0 = fmaf(dv, W[(size_t)c0 * WROW + FF + s2], acc0);
            acc1 = fmaf(dv, W[(size_t)c1 * WROW + FF + s2], acc1);
        }
    }

    // emb @ W^T (all 512 features), second decomposition (vE, cE)
    const int vE = vb + (tid & 15);
    const int cE = (2 * (tid >> 4)) & 127;
    float ea0 = 0.0f, ea1 = 0.0f;
    for (int chk = 0; chk < 16; ++chk) {
        int i0 = 32 * chk;
        const float4* ep = (const float4*)(emb + (size_t)vE * FF + i0);
        const float4* wa = (const float4*)(W + (size_t)cE * WROW + i0);
        const float4* wb = (const float4*)(W + (size_t)(cE + 1) * WROW + i0);
        #pragma unroll
        for (int j = 0; j < 8; ++j) {
            float4 e = ep[j], x = wa[j], y = wb[j];
            ea0 += e.x*x.x + e.y*x.y + e.z*x.z + e.w*x.w;
            ea1 += e.x*y.x + e.y*y.y + e.z*y.z + e.w*y.w;
        }
    }

    // combine decompositions in LDS, add bias, store
    __syncthreads();                       // adjT no longer needed -> reuse
    float* comb = adjT;                    // [16][129] padded
    comb[(tid & 15) * 129 + cE]     = ea0;
    comb[(tid & 15) * 129 + cE + 1] = ea1;
    __syncthreads();
    float o0 = acc0 + comb[vown * 129 + c0] + bias[c0];
    float o1 = acc1 + comb[vown * 129 + c1] + bias[c1];
    *(float2*)(out + (size_t)(vb + vown) * CC + c0) = make_float2(o0, o1);
    if (b == 0 && tid == 0 && out_size > NN * CC)
        out[NN * CC] = hneg ? 1.0f : 0.0f;
}

extern "C" void kernel_launch(void* const* d_in, const int* in_sizes, int n_in,
                              void* d_out, int out_size, void* d_ws, size_t ws_size,
                              hipStream_t stream) {
    const float* adj  = (const float*)d_in[0];
    const float* emb  = (const float*)d_in[1];
    const float* W    = (const float*)d_in[2];
    const float* bias = (const float*)d_in[3];
    const int*   srcp = (const int*)d_in[4];
    float* outp = (float*)d_out;
    WS* ws = (WS*)d_ws;
    int osz = out_size;

    bf_lean<<<dim3(NB), dim3(NT), 0, stream>>>(adj, emb, W, bias, srcp,
                                               outp, ws, osz);
}